// Round 1
// baseline (263.127 us; speedup 1.0000x reference)
//
#include <hip/hip_runtime.h>

// LinearConv2D: y[b, o=g*8+n, fi, t] =
//   sum_{d<8, fr<2, w<16} x[b, g*8+d, 2*fi+fr, 4*t+w] * wt[g*8+n, d, 2*fi+fr, w]
// Shapes: x[16,64,128,256] f32, wt[64,8,128,16] f32, out[16,64,64,61] f32.
// Block = (b,g,fi), 64 lanes = t (61 active). x rows are read by exactly one
// block -> ~1x HBM traffic. Weight loads are wave-uniform -> scalar pipe.

namespace {
constexpr int kB  = 16;
constexpr int kC  = 64;
constexpr int kF  = 128;
constexpr int kT  = 256;
constexpr int kG  = 8;
constexpr int kD  = 8;
constexpr int kN  = 8;
constexpr int kW  = 16;
constexpr int kKS = 4;
constexpr int kNT = 61;   // (256-16)/4 + 1
constexpr int kO  = 64;
constexpr int kFP = 64;   // (128-2)/2 + 1
}

__global__ __launch_bounds__(64, 4)
void lc2d_kernel(const float* __restrict__ x,
                 const float* __restrict__ wt,
                 float* __restrict__ out) {
  const int t  = threadIdx.x;   // 0..63, 61 active
  const int fi = blockIdx.x;    // 0..63
  const int g  = blockIdx.y;    // 0..7
  const int b  = blockIdx.z;    // 0..15

  // Clamp inactive lanes so their (dead) loads stay in-bounds.
  const int tc   = (t < kNT - 1) ? t : (kNT - 1);
  const int tau0 = tc * kKS;    // max 240; +15 = 255 in bounds

  // x[b, g*8+d, 2*fi+fr, tau]
  const float* xbase = x + (((size_t)b * kC + g * kD) * kF + fi * 2) * kT;
  // wt[(g*8+n)*kD*kF*kW + ...] with f = 2*fi+fr
  const float* wbase = wt + ((size_t)(g * kN) * kD * kF + fi * 2) * (size_t)kW;

  float acc[kN];
#pragma unroll
  for (int n = 0; n < kN; ++n) acc[n] = 0.f;

  for (int d = 0; d < kD; ++d) {
#pragma unroll
    for (int fr = 0; fr < 2; ++fr) {
      const float* xr = xbase + ((size_t)d * kF + fr) * kT + tau0;
      const float4 v0 = *(const float4*)(xr + 0);
      const float4 v1 = *(const float4*)(xr + 4);
      const float4 v2 = *(const float4*)(xr + 8);
      const float4 v3 = *(const float4*)(xr + 12);
      const float xv[16] = {v0.x, v0.y, v0.z, v0.w,
                            v1.x, v1.y, v1.z, v1.w,
                            v2.x, v2.y, v2.z, v2.w,
                            v3.x, v3.y, v3.z, v3.w};
#pragma unroll
      for (int n = 0; n < kN; ++n) {
        // Uniform address (blockIdx + loop indices only) -> s_load
        const float* wr = wbase + (((size_t)n * kD + d) * kF + fr) * (size_t)kW;
#pragma unroll
        for (int wq = 0; wq < 4; ++wq) {
          const float4 wv = *(const float4*)(wr + 4 * wq);
          acc[n] = fmaf(xv[4 * wq + 0], wv.x, acc[n]);
          acc[n] = fmaf(xv[4 * wq + 1], wv.y, acc[n]);
          acc[n] = fmaf(xv[4 * wq + 2], wv.z, acc[n]);
          acc[n] = fmaf(xv[4 * wq + 3], wv.w, acc[n]);
        }
      }
    }
  }

  if (t < kNT) {
    float* ob = out + (((size_t)b * kO + g * kN) * kFP + fi) * (size_t)kNT + t;
#pragma unroll
    for (int n = 0; n < kN; ++n) {
      ob[(size_t)n * kFP * kNT] = acc[n];
    }
  }
}

extern "C" void kernel_launch(void* const* d_in, const int* in_sizes, int n_in,
                              void* d_out, int out_size, void* d_ws, size_t ws_size,
                              hipStream_t stream) {
  const float* x  = (const float*)d_in[0];
  const float* wt = (const float*)d_in[1];
  float* out      = (float*)d_out;

  dim3 grid(kFP, kG, kB);   // 64 x 8 x 16 = 8192 blocks
  lc2d_kernel<<<grid, 64, 0, stream>>>(x, wt, out);
}